// Round 7
// baseline (2146.050 us; speedup 1.0000x reference)
//
#include <hip/hip_runtime.h>

#define BB 8
#define IMG 224
#define DD 768
#define NLAY 12
#define DI 1536
#define DS 16
#define DTR 48
#define NPATCH 196
#define L_SEQ 196
#define M_ROWS 1568   // BB*NPATCH
#define MPAD 1664     // 13*128 row padding for A operands
#define DCONV 4
#define NC 14
#define LC 14
#define NCH 13        // stored chunk states (last chunk's partial is never consumed)

typedef _Float16 f16x8 __attribute__((ext_vector_type(8)));
typedef _Float16 f16x4 __attribute__((ext_vector_type(4)));
typedef float f32x4 __attribute__((ext_vector_type(4)));

__device__ __forceinline__ void gll16(const void* g, void* l) {
    __builtin_amdgcn_global_load_lds(
        (const __attribute__((address_space(1))) unsigned int*)g,
        (__attribute__((address_space(3))) unsigned int*)l,
        16, 0, 0);
}

// ---------------- split fp32 -> (hi,lo) f16, 4 elems/thread ----------------
__global__ __launch_bounds__(256) void split4_k(const float* __restrict__ in,
    _Float16* __restrict__ hi, _Float16* __restrict__ lo, int n4)
{
    int i = blockIdx.x * 256 + threadIdx.x;
    if (i >= n4) return;
    float4 v = ((const float4*)in)[i];
    _Float16 h0 = (_Float16)v.x, h1 = (_Float16)v.y, h2 = (_Float16)v.z, h3 = (_Float16)v.w;
    f16x4 H = {h0, h1, h2, h3};
    f16x4 L = {(_Float16)(v.x - (float)h0), (_Float16)(v.y - (float)h1),
               (_Float16)(v.z - (float)h2), (_Float16)(v.w - (float)h3)};
    ((f16x4*)hi)[i] = H;
    ((f16x4*)lo)[i] = L;
}

// ---------------- fp32 -> f16 hi only (weights for 2-term GEMMs) ----------------
__global__ __launch_bounds__(256) void split4hi_k(const float* __restrict__ in,
    _Float16* __restrict__ hi, int n4)
{
    int i = blockIdx.x * 256 + threadIdx.x;
    if (i >= n4) return;
    float4 v = ((const float4*)in)[i];
    f16x4 H = {(_Float16)v.x, (_Float16)v.y, (_Float16)v.z, (_Float16)v.w};
    ((f16x4*)hi)[i] = H;
}

// ---------------- layer-batched split with zero padding ----------------
__global__ __launch_bounds__(256) void splitpadN_k(const float* __restrict__ in,
    _Float16* __restrict__ hi, _Float16* __restrict__ lo,
    int perIn, int inRows, int inCols, int outLd, int perOut, int total)
{
    int i = blockIdx.x * 256 + threadIdx.x;
    if (i >= total) return;
    int l = i / perOut, j = i % perOut;
    int r = j / outLd, c = j % outLd;
    float v = (r < inRows && c < inCols) ? in[(size_t)l * perIn + r * inCols + c] : 0.f;
    _Float16 h = (_Float16)v;
    hi[i] = h;
    lo[i] = (_Float16)(v - (float)h);
}

// ---------------- im2col with split output ----------------
__global__ __launch_bounds__(256) void im2col_k(const float* __restrict__ x,
    _Float16* __restrict__ hi, _Float16* __restrict__ lo)
{
    int idx = blockIdx.x * 256 + threadIdx.x;
    if (idx >= M_ROWS * DD) return;
    int k = idx % DD;
    int m = idx / DD;
    int b = m / NPATCH;
    int t = m % NPATCH;
    int i = t / 14, j = t % 14;
    int c = k / 256;
    int pq = k % 256;
    int p = pq / 16, q = pq % 16;
    float v = x[(((size_t)b * 3 + c) * IMG + i * 16 + p) * IMG + j * 16 + q];
    _Float16 h = (_Float16)v;
    hi[idx] = h;
    lo[idx] = (_Float16)(v - (float)h);
}

// ---------------- 2-term MFMA GEMM, 128x128, BK=64, dbuf + counted-vmcnt pipeline ----------------
// C[M,N] (fp32) = (Ah+Al)[M,K(lda)] * Bh[N,K]^T. A padded to 128-multiple rows.
// Next-tile staging stays in flight across the barrier (s_waitcnt vmcnt(12), never 0 mid-loop).
// gridDim.z>1: split-K, each z writes its own partial buffer C + z*partStride.
__global__ __launch_bounds__(256) void mgemm128_k(
    const _Float16* __restrict__ Ah, const _Float16* __restrict__ Al,
    const _Float16* __restrict__ Bh,
    float* __restrict__ C, int M, int N, int K, int lda, long partStride)
{
    __shared__ __align__(16) _Float16 As[2][2][128][64];   // [buf][plane][row][k], seg-swizzled
    __shared__ __align__(16) _Float16 Bs[2][128][64];
    int tid = threadIdx.x, lane = tid & 63, wid = tid >> 6;
    int m0 = blockIdx.y * 128, n0 = blockIdx.x * 128;
    int kBeg = 0, nIter = K / 64;
    if (gridDim.z > 1) {
        int kPer = K / gridDim.z;
        kBeg = blockIdx.z * kPer;
        nIter = kPer / 64;
        C += (size_t)blockIdx.z * partStride;
    }

    // staging: wave covers rows [r0, r0+32); per gll16 call: 8 rows x 8 segs of 16B.
    int r0 = wid * 32;
    int lr = lane >> 3;
    int qs = ((lane & 7) ^ lr) * 8;                  // swizzled global k-seg
    const _Float16* AhP = Ah + (size_t)(m0 + r0 + lr) * lda + kBeg + qs;
    const _Float16* AlP = Al + (size_t)(m0 + r0 + lr) * lda + kBeg + qs;
    const _Float16* BhP = Bh + (size_t)(n0 + r0 + lr) * K + kBeg + qs;
    size_t a8 = (size_t)8 * lda, b8 = (size_t)8 * K;

#define STAGE128(sb, it) { int k0 = (it) * 64;                          \
        _Pragma("unroll") for (int j = 0; j < 4; ++j) {                 \
            gll16(AhP + (size_t)j * a8 + k0, &As[sb][0][r0 + 8 * j][0]); \
            gll16(AlP + (size_t)j * a8 + k0, &As[sb][1][r0 + 8 * j][0]); \
            gll16(BhP + (size_t)j * b8 + k0, &Bs[sb][r0 + 8 * j][0]); } }

    int wm = (wid >> 1) * 64, wn = (wid & 1) * 64;
    int lm = lane & 15, quad = lane >> 4;
    int seg0 = (quad ^ (lm & 7)) * 8;                // read-side swizzle, k-chunk 0
    f32x4 acc[4][4] = {};

    STAGE128(0, 0);                                  // 12 loads in flight
    for (int it = 0; it < nIter; ++it) {
        int buf = it & 1;
        if (it + 1 < nIter) {
            STAGE128(buf ^ 1, it + 1);               // +12 -> 24 in flight
            asm volatile("s_waitcnt vmcnt(12)" ::: "memory");   // oldest 12 (cur buf) done
        } else {
            asm volatile("s_waitcnt vmcnt(0)" ::: "memory");
        }
        __builtin_amdgcn_s_barrier();                // all waves' cur-buf staging done

#pragma unroll
        for (int ch = 0; ch < 2; ++ch) {
            int ls = seg0 ^ (ch * 32);
            f16x8 ah[4], al4[4], bh4[4];
#pragma unroll
            for (int i = 0; i < 4; ++i) {
                ah[i]  = *(const f16x8*)&As[buf][0][wm + i * 16 + lm][ls];
                al4[i] = *(const f16x8*)&As[buf][1][wm + i * 16 + lm][ls];
                bh4[i] = *(const f16x8*)&Bs[buf][wn + i * 16 + lm][ls];
            }
#pragma unroll
            for (int mi = 0; mi < 4; ++mi)
#pragma unroll
                for (int ni = 0; ni < 4; ++ni) {
                    acc[mi][ni] = __builtin_amdgcn_mfma_f32_16x16x32_f16(ah[mi],  bh4[ni], acc[mi][ni], 0, 0, 0);
                    acc[mi][ni] = __builtin_amdgcn_mfma_f32_16x16x32_f16(al4[mi], bh4[ni], acc[mi][ni], 0, 0, 0);
                }
        }
        asm volatile("s_waitcnt lgkmcnt(0)" ::: "memory");   // my reads of cur done
        __builtin_amdgcn_s_barrier();                // before anyone re-stages cur
    }
#undef STAGE128

#pragma unroll
    for (int mi = 0; mi < 4; ++mi)
#pragma unroll
        for (int ni = 0; ni < 4; ++ni)
#pragma unroll
            for (int r = 0; r < 4; ++r) {
                int row = m0 + wm + mi * 16 + quad * 4 + r;
                int col = n0 + wn + ni * 16 + lm;
                if (row < M) C[(size_t)row * N + col] = acc[mi][ni][r];
            }
}

// ---------------- f16x3 MFMA GEMM, 64x64x32, dbuf + counted-vmcnt pipeline ----------------
// mode 1: softplus(v+bias[n])  2: v+bias[n]+pos[(m%196)*N+n]  3: atomicAdd (split-K grid.z)
__global__ __launch_bounds__(256) void mgemm_k(
    const _Float16* __restrict__ Ah, const _Float16* __restrict__ Al,
    const _Float16* __restrict__ Bh, const _Float16* __restrict__ Bl,
    float* __restrict__ C, _Float16* __restrict__ Chi, _Float16* __restrict__ Clo,
    int M, int N, int K, int lda, int Nstore,
    const float* __restrict__ bias, const float* __restrict__ pos, int mode)
{
    __shared__ __align__(16) _Float16 As[2][2][64][32];
    __shared__ __align__(16) _Float16 Bs[2][2][64][32];
    int tid = threadIdx.x, lane = tid & 63, wid = tid >> 6;
    int m0 = blockIdx.y * 64, n0 = blockIdx.x * 64;
    int kBeg = 0, nIter = K / 32;
    if (gridDim.z > 1) { int kPer = K / gridDim.z; kBeg = blockIdx.z * kPer; nIter = kPer / 32; }

    int srow = wid * 16 + (lane >> 2);
    int qs = ((lane & 3) ^ ((lane >> 3) & 3)) * 8;
    const _Float16* aH = Ah + (size_t)(m0 + srow) * lda + kBeg + qs;
    const _Float16* aL = Al + (size_t)(m0 + srow) * lda + kBeg + qs;
    const _Float16* bH = Bh + (size_t)(n0 + srow) * K + kBeg + qs;
    const _Float16* bL = Bl + (size_t)(n0 + srow) * K + kBeg + qs;

#define STAGE(buf, it) { int ko = (it) * 32;              \
        gll16(aH + ko, &As[buf][0][wid * 16][0]);          \
        gll16(aL + ko, &As[buf][1][wid * 16][0]);          \
        gll16(bH + ko, &Bs[buf][0][wid * 16][0]);          \
        gll16(bL + ko, &Bs[buf][1][wid * 16][0]); }

    int wm = (wid >> 1) * 32, wn = (wid & 1) * 32;
    int lm = lane & 15, quad = lane >> 4;
    int segA = (quad ^ ((lm >> 1) & 3)) * 8;
    f32x4 acc[2][2] = {};

    STAGE(0, 0);
    for (int it = 0; it < nIter; ++it) {
        int buf = it & 1;
        if (it + 1 < nIter) {
            STAGE(buf ^ 1, it + 1);
            asm volatile("s_waitcnt vmcnt(4)" ::: "memory");
        } else {
            asm volatile("s_waitcnt vmcnt(0)" ::: "memory");
        }
        __builtin_amdgcn_s_barrier();
        f16x8 ah[2], al2[2], bh2[2], bl2[2];
#pragma unroll
        for (int i = 0; i < 2; ++i) {
            ah[i]  = *(const f16x8*)&As[buf][0][wm + i * 16 + lm][segA];
            al2[i] = *(const f16x8*)&As[buf][1][wm + i * 16 + lm][segA];
            bh2[i] = *(const f16x8*)&Bs[buf][0][wn + i * 16 + lm][segA];
            bl2[i] = *(const f16x8*)&Bs[buf][1][wn + i * 16 + lm][segA];
        }
#pragma unroll
        for (int mi = 0; mi < 2; ++mi)
#pragma unroll
            for (int ni = 0; ni < 2; ++ni) {
                acc[mi][ni] = __builtin_amdgcn_mfma_f32_16x16x32_f16(ah[mi],  bh2[ni], acc[mi][ni], 0, 0, 0);
                acc[mi][ni] = __builtin_amdgcn_mfma_f32_16x16x32_f16(ah[mi],  bl2[ni], acc[mi][ni], 0, 0, 0);
                acc[mi][ni] = __builtin_amdgcn_mfma_f32_16x16x32_f16(al2[mi], bh2[ni], acc[mi][ni], 0, 0, 0);
            }
        asm volatile("s_waitcnt lgkmcnt(0)" ::: "memory");
        __builtin_amdgcn_s_barrier();
    }
#undef STAGE

#pragma unroll
    for (int mi = 0; mi < 2; ++mi)
#pragma unroll
        for (int ni = 0; ni < 2; ++ni)
#pragma unroll
            for (int r = 0; r < 4; ++r) {
                int row = m0 + wm + mi * 16 + quad * 4 + r;
                int col = n0 + wn + ni * 16 + lm;
                if (row >= M || col >= Nstore) continue;
                float v = acc[mi][ni][r];
                if (mode == 1) { v += bias[col]; v = (v > 20.f) ? v : log1pf(__expf(v)); }
                else if (mode == 2) v += bias[col] + pos[(size_t)(row % NPATCH) * N + col];
                size_t idx = (size_t)row * N + col;
                if (mode == 3) { atomicAdd(&C[idx], v); continue; }
                if (C) C[idx] = v;
                if (Chi) {
                    _Float16 h = (_Float16)v;
                    Chi[idx] = h;
                    Clo[idx] = (_Float16)(v - (float)h);
                }
            }
}

// ---------------- causal depthwise conv (k=4) + SiLU -> f16 split, 4 elems/thread ----------------
// also zero-fills projb (for the following split-K atomic x_proj GEMM)
__global__ __launch_bounds__(256) void conv_k(
    const float* __restrict__ xz, const float* __restrict__ cw,
    const float* __restrict__ cb, _Float16* __restrict__ xch, _Float16* __restrict__ xcl,
    float* __restrict__ projb)
{
    int i4 = blockIdx.x * 256 + threadIdx.x;
    if (i4 >= M_ROWS * DI / 4) return;
    if (i4 < M_ROWS * 20) ((float4*)projb)[i4] = float4{0.f, 0.f, 0.f, 0.f};
    int e4 = i4 % (DI / 4);
    int m  = i4 / (DI / 4);
    int e  = e4 * 4;
    int l  = m % L_SEQ;
    float4 acc = *(const float4*)&cb[e];
    const float4* cwv = (const float4*)&cw[e * DCONV];   // cwv[j] = taps 0..3 of elem e+j
    float4 c0 = cwv[0], c1 = cwv[1], c2 = cwv[2], c3 = cwv[3];
#pragma unroll
    for (int k = 0; k < DCONV; ++k) {
        int ls = l + k - (DCONV - 1);
        if (ls >= 0) {
            float4 v = *(const float4*)&xz[(size_t)(m + k - (DCONV - 1)) * (2 * DI) + e];
            acc.x += (&c0.x)[k] * v.x;
            acc.y += (&c1.x)[k] * v.y;
            acc.z += (&c2.x)[k] * v.z;
            acc.w += (&c3.x)[k] * v.w;
        }
    }
    float r0 = acc.x / (1.f + __expf(-acc.x));
    float r1 = acc.y / (1.f + __expf(-acc.y));
    float r2 = acc.z / (1.f + __expf(-acc.z));
    float r3 = acc.w / (1.f + __expf(-acc.w));
    _Float16 h0 = (_Float16)r0, h1 = (_Float16)r1, h2 = (_Float16)r2, h3 = (_Float16)r3;
    f16x4 H = {h0, h1, h2, h3};
    f16x4 L = {(_Float16)(r0 - (float)h0), (_Float16)(r1 - (float)h1),
               (_Float16)(r2 - (float)h2), (_Float16)(r3 - (float)h3)};
    ((f16x4*)xch)[i4] = H;
    ((f16x4*)xcl)[i4] = L;
}

// ================= chunked selective scan (2 passes, dt_proj fused) =================
__global__ __launch_bounds__(64) void scanA_k(
    const _Float16* __restrict__ xch, const _Float16* __restrict__ xcl,
    const float* __restrict__ proj, const float* __restrict__ dtw,
    const float* __restrict__ dtb, const float* __restrict__ A_log,
    float* __restrict__ hpart, float* __restrict__ Sdt)
{
    int d = blockIdx.x * 64 + threadIdx.x;
    int b = blockIdx.y, c = blockIdx.z;
    float Aa[DS];
#pragma unroll
    for (int s = 0; s < DS; ++s) Aa[s] = -__expf(A_log[d * DS + s]);
    float W[DTR];
    const float4* Wp = (const float4*)(dtw + (size_t)d * DTR);
#pragma unroll
    for (int i = 0; i < DTR / 4; ++i) {
        float4 w = Wp[i];
        W[4 * i] = w.x; W[4 * i + 1] = w.y; W[4 * i + 2] = w.z; W[4 * i + 3] = w.w;
    }
    float bia = dtb[d];
    float h[DS];
#pragma unroll
    for (int s = 0; s < DS; ++s) h[s] = 0.f;
    float sdt = 0.f;
    size_t base = (size_t)b * L_SEQ + c * LC;
    for (int l = 0; l < LC; ++l) {
        size_t ii = (base + l) * DI + d;
        const float* pr = proj + (base + l) * 80;
        float draw = bia;
#pragma unroll
        for (int r = 0; r < DTR; ++r) draw += pr[r] * W[r];
        float dtv = (draw > 20.f) ? draw : log1pf(__expf(draw));
        float xv  = (float)xch[ii] + (float)xcl[ii];
        float dx = dtv * xv;
        sdt += dtv;
#pragma unroll
        for (int s = 0; s < DS; ++s)
            h[s] = __expf(dtv * Aa[s]) * h[s] + dx * pr[DTR + s];
    }
    size_t o = (size_t)(b * NCH + c) * DS * DI + d;
#pragma unroll
    for (int s = 0; s < DS; ++s) hpart[o + (size_t)s * DI] = h[s];
    Sdt[(size_t)(b * NCH + c) * DI + d] = sdt;
}

// scanC: self-computed chunk prefix, dt_proj fused, emits y (silu-gated, split)
__global__ __launch_bounds__(64) void scanC_k(
    const _Float16* __restrict__ xch, const _Float16* __restrict__ xcl,
    const float* __restrict__ proj, const float* __restrict__ xz,
    const float* __restrict__ dtw, const float* __restrict__ dtb,
    const float* __restrict__ A_log, const float* __restrict__ Dp,
    const float* __restrict__ hpart, const float* __restrict__ Sdt,
    _Float16* __restrict__ yh, _Float16* __restrict__ yl)
{
    int d = blockIdx.x * 64 + threadIdx.x;
    int b = blockIdx.y, c = blockIdx.z;
    float Aa[DS];
#pragma unroll
    for (int s = 0; s < DS; ++s) Aa[s] = -__expf(A_log[d * DS + s]);
    float W[DTR];
    const float4* Wp = (const float4*)(dtw + (size_t)d * DTR);
#pragma unroll
    for (int i = 0; i < DTR / 4; ++i) {
        float4 w = Wp[i];
        W[4 * i] = w.x; W[4 * i + 1] = w.y; W[4 * i + 2] = w.z; W[4 * i + 3] = w.w;
    }
    float bia = dtb[d];
    float h[DS];
#pragma unroll
    for (int s = 0; s < DS; ++s) h[s] = 0.f;
    for (int cc = 0; cc < c; ++cc) {
        float sdt = Sdt[(size_t)(b * NCH + cc) * DI + d];
        size_t o = (size_t)(b * NCH + cc) * DS * DI + d;
#pragma unroll
        for (int s = 0; s < DS; ++s)
            h[s] = __expf(Aa[s] * sdt) * h[s] + hpart[o + (size_t)s * DI];
    }
    float dP = Dp[d];
    size_t base = (size_t)b * L_SEQ + c * LC;
    for (int l = 0; l < LC; ++l) {
        size_t ii = (base + l) * DI + d;
        const float* pr = proj + (base + l) * 80;
        float draw = bia;
#pragma unroll
        for (int r = 0; r < DTR; ++r) draw += pr[r] * W[r];
        float dtv = (draw > 20.f) ? draw : log1pf(__expf(draw));
        float xv  = (float)xch[ii] + (float)xcl[ii];
        float zv  = xz[(base + l) * 2 * DI + DI + d];
        float dx = dtv * xv;
        float accv = 0.f;
#pragma unroll
        for (int s = 0; s < DS; ++s) {
            h[s] = __expf(dtv * Aa[s]) * h[s] + dx * pr[DTR + s];
            accv += h[s] * pr[DTR + DS + s];
        }
        float yv = accv + xv * dP;
        float sg = 1.f / (1.f + __expf(-zv));
        float vy = yv * (zv * sg);
        _Float16 hh = (_Float16)vy;
        yh[ii] = hh;
        yl[ii] = (_Float16)(vy - (float)hh);
    }
}

// ---------------- sum 4 split-K partials -> f16 hi/lo split ----------------
__global__ __launch_bounds__(256) void red4split_k(const float* __restrict__ part,
    _Float16* __restrict__ hi, _Float16* __restrict__ lo, int n4, int stride4)
{
    int i = blockIdx.x * 256 + threadIdx.x;
    if (i >= n4) return;
    const float4* p = (const float4*)part;
    float4 a = p[i], b = p[i + stride4], c = p[i + 2 * stride4], e = p[i + 3 * stride4];
    float x0 = a.x + b.x + c.x + e.x;
    float x1 = a.y + b.y + c.y + e.y;
    float x2 = a.z + b.z + c.z + e.z;
    float x3 = a.w + b.w + c.w + e.w;
    _Float16 h0 = (_Float16)x0, h1 = (_Float16)x1, h2 = (_Float16)x2, h3 = (_Float16)x3;
    f16x4 H = {h0, h1, h2, h3};
    f16x4 L = {(_Float16)(x0 - (float)h0), (_Float16)(x1 - (float)h1),
               (_Float16)(x2 - (float)h2), (_Float16)(x3 - (float)h3)};
    ((f16x4*)hi)[i] = H;
    ((f16x4*)lo)[i] = L;
}

// ---------------- layernorm over D=768 from f16 hi+lo ----------------
__global__ __launch_bounds__(256) void ln_k(const _Float16* __restrict__ hh,
    const _Float16* __restrict__ hl,
    const float* __restrict__ w, const float* __restrict__ bias, float* __restrict__ out)
{
    int row = blockIdx.x;
    int tid = threadIdx.x;
    size_t base = (size_t)row * DD;
    float v0 = (float)hh[base + tid]       + (float)hl[base + tid];
    float v1 = (float)hh[base + tid + 256] + (float)hl[base + tid + 256];
    float v2 = (float)hh[base + tid + 512] + (float)hl[base + tid + 512];
    float s = v0 + v1 + v2;
    __shared__ float red[4];
    for (int off = 32; off; off >>= 1) s += __shfl_down(s, off);
    if ((tid & 63) == 0) red[tid >> 6] = s;
    __syncthreads();
    float mu = (red[0] + red[1] + red[2] + red[3]) * (1.f / 768.f);
    __syncthreads();
    float d0 = v0 - mu, d1 = v1 - mu, d2 = v2 - mu;
    float vs = d0 * d0 + d1 * d1 + d2 * d2;
    for (int off = 32; off; off >>= 1) vs += __shfl_down(vs, off);
    if ((tid & 63) == 0) red[tid >> 6] = vs;
    __syncthreads();
    float var = (red[0] + red[1] + red[2] + red[3]) * (1.f / 768.f);
    float rs = rsqrtf(var + 1e-5f);
    out[base + tid]       = d0 * rs * w[tid]       + bias[tid];
    out[base + tid + 256] = d1 * rs * w[tid + 256] + bias[tid + 256];
    out[base + tid + 512] = d2 * rs * w[tid + 512] + bias[tid + 512];
}

extern "C" void kernel_launch(void* const* d_in, const int* in_sizes, int n_in,
                              void* d_out, int out_size, void* d_ws, size_t ws_size,
                              hipStream_t stream) {
    const float* x        = (const float*)d_in[0];
    const float* patch_w  = (const float*)d_in[1];
    const float* patch_b  = (const float*)d_in[2];
    const float* pos      = (const float*)d_in[3];
    const float* in_proj  = (const float*)d_in[4];
    const float* conv_w   = (const float*)d_in[5];
    const float* conv_b   = (const float*)d_in[6];
    const float* x_proj   = (const float*)d_in[7];
    const float* dt_w     = (const float*)d_in[8];
    const float* dt_b     = (const float*)d_in[9];
    const float* A_log    = (const float*)d_in[10];
    const float* D_param  = (const float*)d_in[11];
    const float* out_w    = (const float*)d_in[12];
    const float* norm_w   = (const float*)d_in[13];
    const float* norm_b   = (const float*)d_in[14];
    float* out = (float*)d_out;

    // fp32 workspace
    float* ws    = (float*)d_ws;
    float* xzb   = ws;                      // 4,816,896 (1568*3072)
    float* projb = xzb   + 4816896;         //   125,440
    float* hpart = projb + 125440;          // 2,555,904 (8*13*16*1536)
    float* sdtb  = hpart + 2555904;         //   159,744 (8*13*1536)
    float* opart = sdtb  + 159744;          // 4,816,896 (4 x 1568*768 split-K partials)
    // f16 workspace (A-operand buffers padded to MPAD=1664 rows)
    _Float16* fp  = (_Float16*)(opart + 4816896);
    _Float16* hbh = fp;                     // 1664*768
    _Float16* hbl = hbh + MPAD * DD;
    _Float16* yh  = hbl + MPAD * DD;        // 1664*1536 (also im2col out)
    _Float16* yl  = yh  + MPAD * DI;
    _Float16* xch = yl  + MPAD * DI;        // 1664*1536
    _Float16* xcl = xch + MPAD * DI;
    _Float16* pwh = xcl + MPAD * DI;        // 768*768
    _Float16* pwl = pwh + 589824;
    // all-layer weight splits (in/out proj: hi-plane only, 2-term GEMM)
    _Float16* wih = pwl + 589824;           // 12 * 3072*768
    _Float16* woh = wih + (size_t)NLAY * 2359296;   // 12 * 768*1536
    _Float16* xwh = woh + (size_t)NLAY * 1179648;   // 12 * 128*1536 (row-padded)
    _Float16* xwl = xwh + (size_t)NLAY * 196608;

    // ---- weight splits, batched over layers ----
    split4hi_k<<<(NLAY * 2359296 / 4 + 255) / 256, 256, 0, stream>>>(in_proj, wih, NLAY * 2359296 / 4);
    split4hi_k<<<(NLAY * 1179648 / 4 + 255) / 256, 256, 0, stream>>>(out_w, woh, NLAY * 1179648 / 4);
    splitpadN_k<<<(NLAY * 196608 + 255) / 256, 256, 0, stream>>>(
        x_proj, xwh, xwl, 80 * DI, 80, DI, DI, 196608, NLAY * 196608);
    split4_k<<<(589824 / 4 + 255) / 256, 256, 0, stream>>>(patch_w, pwh, pwl, 589824 / 4);

    // ---- patch embed ----
    im2col_k<<<(M_ROWS * DD + 255) / 256, 256, 0, stream>>>(x, yh, yl);
    mgemm_k<<<dim3(12, 25), 256, 0, stream>>>(yh, yl, pwh, pwl,
        nullptr, hbh, hbl, M_ROWS, DD, DD, DD, DD, patch_b, pos, 2);

    for (int l = 0; l < NLAY; ++l) {
        const float* Al  = A_log + (size_t)l * DI * DS;
        const float* Wdt = dt_w  + (size_t)l * DI * DTR;
        const float* Bdt = dt_b  + (size_t)l * DI;
        // in_proj: (1568,768) x (3072,768)^T -> xz fp32 (128x128 BK=64 pipelined)
        mgemm128_k<<<dim3(24, 13), 256, 0, stream>>>(hbh, hbl,
            wih + (size_t)l * 2359296,
            xzb, M_ROWS, 2 * DI, DD, DD, 0);
        // conv + silu -> xc split; also zeroes projb for the atomic GEMM
        conv_k<<<(M_ROWS * DI / 4) / 256, 256, 0, stream>>>(xzb, conv_w + (size_t)l * DI * DCONV,
                                                            conv_b + (size_t)l * DI, xch, xcl, projb);
        // x_proj: split-K=4 atomic -> projb fp32 (f16x3 precision)
        mgemm_k<<<dim3(2, 25, 4), 256, 0, stream>>>(xch, xcl,
            xwh + (size_t)l * 196608, xwl + (size_t)l * 196608,
            projb, nullptr, nullptr, M_ROWS, 80, DI, DI, 80, nullptr, nullptr, 3);
        // chunked scan, dt_proj fused in (fp32 dot), scanB absorbed into scanC prefix
        scanA_k<<<dim3(DI / 64, BB, NCH), 64, 0, stream>>>(xch, xcl, projb, Wdt, Bdt, Al, hpart, sdtb);
        scanC_k<<<dim3(DI / 64, BB, NC), 64, 0, stream>>>(xch, xcl, projb, xzb, Wdt, Bdt, Al,
                                                          D_param + (size_t)l * DI, hpart, sdtb, yh, yl);
        // out_proj: 128x128 BK=64 pipelined split-K=4 -> 4 partial buffers, then reduce+split
        mgemm128_k<<<dim3(6, 13, 4), 256, 0, stream>>>(yh, yl,
            woh + (size_t)l * 1179648,
            opart, M_ROWS, DD, DI, DI, (long)M_ROWS * DD);
        red4split_k<<<(M_ROWS * DD / 4 + 255) / 256, 256, 0, stream>>>(
            opart, hbh, hbl, M_ROWS * DD / 4, M_ROWS * DD / 4);
    }

    ln_k<<<M_ROWS, 256, 0, stream>>>(hbh, hbl, norm_w, norm_b, out);
}

// Round 8
// 1874.694 us; speedup vs baseline: 1.1447x; 1.1447x over previous
//
#include <hip/hip_runtime.h>

#define BB 8
#define IMG 224
#define DD 768
#define NLAY 12
#define DI 1536
#define DS 16
#define DTR 48
#define NPATCH 196
#define L_SEQ 196
#define M_ROWS 1568   // BB*NPATCH
#define MPAD 1664     // 13*128 row padding for A operands
#define DCONV 4
#define NC 14
#define LC 14
#define NCH 13        // stored chunk states (last chunk's partial is never consumed)
#define XZPS 4816896  // in_proj split-K partial stride (M_ROWS*2*DI floats)

typedef _Float16 f16x8 __attribute__((ext_vector_type(8)));
typedef _Float16 f16x4 __attribute__((ext_vector_type(4)));
typedef float f32x4 __attribute__((ext_vector_type(4)));

__device__ __forceinline__ void gll16(const void* g, void* l) {
    __builtin_amdgcn_global_load_lds(
        (const __attribute__((address_space(1))) unsigned int*)g,
        (__attribute__((address_space(3))) unsigned int*)l,
        16, 0, 0);
}

// ---------------- split fp32 -> (hi,lo) f16, 4 elems/thread ----------------
__global__ __launch_bounds__(256) void split4_k(const float* __restrict__ in,
    _Float16* __restrict__ hi, _Float16* __restrict__ lo, int n4)
{
    int i = blockIdx.x * 256 + threadIdx.x;
    if (i >= n4) return;
    float4 v = ((const float4*)in)[i];
    _Float16 h0 = (_Float16)v.x, h1 = (_Float16)v.y, h2 = (_Float16)v.z, h3 = (_Float16)v.w;
    f16x4 H = {h0, h1, h2, h3};
    f16x4 L = {(_Float16)(v.x - (float)h0), (_Float16)(v.y - (float)h1),
               (_Float16)(v.z - (float)h2), (_Float16)(v.w - (float)h3)};
    ((f16x4*)hi)[i] = H;
    ((f16x4*)lo)[i] = L;
}

// ---------------- fp32 -> f16 hi only (weights for 2-term GEMMs) ----------------
__global__ __launch_bounds__(256) void split4hi_k(const float* __restrict__ in,
    _Float16* __restrict__ hi, int n4)
{
    int i = blockIdx.x * 256 + threadIdx.x;
    if (i >= n4) return;
    float4 v = ((const float4*)in)[i];
    f16x4 H = {(_Float16)v.x, (_Float16)v.y, (_Float16)v.z, (_Float16)v.w};
    ((f16x4*)hi)[i] = H;
}

// ---------------- layer-batched split with zero padding ----------------
__global__ __launch_bounds__(256) void splitpadN_k(const float* __restrict__ in,
    _Float16* __restrict__ hi, _Float16* __restrict__ lo,
    int perIn, int inRows, int inCols, int outLd, int perOut, int total)
{
    int i = blockIdx.x * 256 + threadIdx.x;
    if (i >= total) return;
    int l = i / perOut, j = i % perOut;
    int r = j / outLd, c = j % outLd;
    float v = (r < inRows && c < inCols) ? in[(size_t)l * perIn + r * inCols + c] : 0.f;
    _Float16 h = (_Float16)v;
    hi[i] = h;
    lo[i] = (_Float16)(v - (float)h);
}

// ---------------- im2col with split output ----------------
__global__ __launch_bounds__(256) void im2col_k(const float* __restrict__ x,
    _Float16* __restrict__ hi, _Float16* __restrict__ lo)
{
    int idx = blockIdx.x * 256 + threadIdx.x;
    if (idx >= M_ROWS * DD) return;
    int k = idx % DD;
    int m = idx / DD;
    int b = m / NPATCH;
    int t = m % NPATCH;
    int i = t / 14, j = t % 14;
    int c = k / 256;
    int pq = k % 256;
    int p = pq / 16, q = pq % 16;
    float v = x[(((size_t)b * 3 + c) * IMG + i * 16 + p) * IMG + j * 16 + q];
    _Float16 h = (_Float16)v;
    hi[idx] = h;
    lo[idx] = (_Float16)(v - (float)h);
}

// ---------------- 2-term MFMA GEMM, 128x128, BK=64: (Ah+Al) x Bh^T ----------------
// C[M,N] (fp32) = (Ah+Al)[M,K(lda)] * Bh[N,K]^T. A padded to 128-multiple rows.
// BK=64 halves the barrier/vmcnt-drain count vs BK=32 (drain-latency-bound at low blocks/CU).
// gridDim.z>1: split-K, each z writes its own partial buffer C + z*partStride.
__global__ __launch_bounds__(256) void mgemm128_k(
    const _Float16* __restrict__ Ah, const _Float16* __restrict__ Al,
    const _Float16* __restrict__ Bh,
    float* __restrict__ C, int M, int N, int K, int lda, long partStride)
{
    __shared__ __align__(16) _Float16 As[2][128][64];   // [plane][row][k], seg-swizzled
    __shared__ __align__(16) _Float16 Bs[128][64];
    int tid = threadIdx.x, lane = tid & 63, wid = tid >> 6;
    int m0 = blockIdx.y * 128, n0 = blockIdx.x * 128;
    int kBeg = 0, nIter = K / 64;
    if (gridDim.z > 1) {
        int kPer = K / gridDim.z;
        kBeg = blockIdx.z * kPer;
        nIter = kPer / 64;
        C += (size_t)blockIdx.z * partStride;
    }

    // staging: wave covers rows [r0, r0+32); per gll16 call: 8 rows x 8 segs of 16B.
    // lane -> row r0+8j+(lane>>3), global k-seg ((lane&7)^(lane>>3)) [store swizzle]
    int r0 = wid * 32;
    int lr = lane >> 3;
    int qs = ((lane & 7) ^ lr) * 8;                  // swizzled global k-seg (halves)
    const _Float16* AhP = Ah + (size_t)(m0 + r0 + lr) * lda + kBeg + qs;
    const _Float16* AlP = Al + (size_t)(m0 + r0 + lr) * lda + kBeg + qs;
    const _Float16* BhP = Bh + (size_t)(n0 + r0 + lr) * K + kBeg + qs;
    size_t a8 = (size_t)8 * lda, b8 = (size_t)8 * K;

    int wm = (wid >> 1) * 64, wn = (wid & 1) * 64;
    int lm = lane & 15, quad = lane >> 4;
    int seg0 = (quad ^ (lm & 7)) * 8;                // read-side swizzle, k-chunk 0
    f32x4 acc[4][4] = {};

    for (int it = 0; it < nIter; ++it) {
        int k0 = it * 64;
#pragma unroll
        for (int j = 0; j < 4; ++j) {
            gll16(AhP + (size_t)j * a8 + k0, &As[0][r0 + 8 * j][0]);
            gll16(AlP + (size_t)j * a8 + k0, &As[1][r0 + 8 * j][0]);
            gll16(BhP + (size_t)j * b8 + k0, &Bs[r0 + 8 * j][0]);
        }
        __syncthreads();

#pragma unroll
        for (int ch = 0; ch < 2; ++ch) {
            int ls = seg0 ^ (ch * 32);               // ((quad^4ch)^(lm&7))*8
            f16x8 ah[4], al4[4], bh4[4];
#pragma unroll
            for (int i = 0; i < 4; ++i) {
                ah[i]  = *(const f16x8*)&As[0][wm + i * 16 + lm][ls];
                al4[i] = *(const f16x8*)&As[1][wm + i * 16 + lm][ls];
                bh4[i] = *(const f16x8*)&Bs[wn + i * 16 + lm][ls];
            }
#pragma unroll
            for (int mi = 0; mi < 4; ++mi)
#pragma unroll
                for (int ni = 0; ni < 4; ++ni) {
                    acc[mi][ni] = __builtin_amdgcn_mfma_f32_16x16x32_f16(ah[mi],  bh4[ni], acc[mi][ni], 0, 0, 0);
                    acc[mi][ni] = __builtin_amdgcn_mfma_f32_16x16x32_f16(al4[mi], bh4[ni], acc[mi][ni], 0, 0, 0);
                }
        }
        __syncthreads();
    }

#pragma unroll
    for (int mi = 0; mi < 4; ++mi)
#pragma unroll
        for (int ni = 0; ni < 4; ++ni)
#pragma unroll
            for (int r = 0; r < 4; ++r) {
                int row = m0 + wm + mi * 16 + quad * 4 + r;
                int col = n0 + wn + ni * 16 + lm;
                if (row < M) C[(size_t)row * N + col] = acc[mi][ni][r];
            }
}

// ---------------- f16x3 MFMA GEMM, 64x64x32, dbuf, swizzled ----------------
// mode 1: softplus(v+bias[n])  2: v+bias[n]+pos[(m%196)*N+n]  3: atomicAdd (split-K grid.z)
__global__ __launch_bounds__(256) void mgemm_k(
    const _Float16* __restrict__ Ah, const _Float16* __restrict__ Al,
    const _Float16* __restrict__ Bh, const _Float16* __restrict__ Bl,
    float* __restrict__ C, _Float16* __restrict__ Chi, _Float16* __restrict__ Clo,
    int M, int N, int K, int lda, int Nstore,
    const float* __restrict__ bias, const float* __restrict__ pos, int mode)
{
    __shared__ __align__(16) _Float16 As[2][2][64][32];
    __shared__ __align__(16) _Float16 Bs[2][2][64][32];
    int tid = threadIdx.x, lane = tid & 63, wid = tid >> 6;
    int m0 = blockIdx.y * 64, n0 = blockIdx.x * 64;
    int kBeg = 0, nIter = K / 32;
    if (gridDim.z > 1) { int kPer = K / gridDim.z; kBeg = blockIdx.z * kPer; nIter = kPer / 32; }

    int srow = wid * 16 + (lane >> 2);
    int qs = ((lane & 3) ^ ((lane >> 3) & 3)) * 8;
    const _Float16* aH = Ah + (size_t)(m0 + srow) * lda + kBeg + qs;
    const _Float16* aL = Al + (size_t)(m0 + srow) * lda + kBeg + qs;
    const _Float16* bH = Bh + (size_t)(n0 + srow) * K + kBeg + qs;
    const _Float16* bL = Bl + (size_t)(n0 + srow) * K + kBeg + qs;

#define STAGE(buf, it) { int ko = (it) * 32;              \
        gll16(aH + ko, &As[buf][0][wid * 16][0]);          \
        gll16(aL + ko, &As[buf][1][wid * 16][0]);          \
        gll16(bH + ko, &Bs[buf][0][wid * 16][0]);          \
        gll16(bL + ko, &Bs[buf][1][wid * 16][0]); }

    int wm = (wid >> 1) * 32, wn = (wid & 1) * 32;
    int lm = lane & 15, quad = lane >> 4;
    int segA = (quad ^ ((lm >> 1) & 3)) * 8;
    f32x4 acc[2][2] = {};

    STAGE(0, 0);
    for (int it = 0; it < nIter; ++it) {
        int buf = it & 1;
        if (it + 1 < nIter) STAGE(buf ^ 1, it + 1);
        __syncthreads();
        f16x8 ah[2], al2[2], bh2[2], bl2[2];
#pragma unroll
        for (int i = 0; i < 2; ++i) {
            ah[i]  = *(const f16x8*)&As[buf][0][wm + i * 16 + lm][segA];
            al2[i] = *(const f16x8*)&As[buf][1][wm + i * 16 + lm][segA];
            bh2[i] = *(const f16x8*)&Bs[buf][0][wn + i * 16 + lm][segA];
            bl2[i] = *(const f16x8*)&Bs[buf][1][wn + i * 16 + lm][segA];
        }
#pragma unroll
        for (int mi = 0; mi < 2; ++mi)
#pragma unroll
            for (int ni = 0; ni < 2; ++ni) {
                acc[mi][ni] = __builtin_amdgcn_mfma_f32_16x16x32_f16(ah[mi],  bh2[ni], acc[mi][ni], 0, 0, 0);
                acc[mi][ni] = __builtin_amdgcn_mfma_f32_16x16x32_f16(ah[mi],  bl2[ni], acc[mi][ni], 0, 0, 0);
                acc[mi][ni] = __builtin_amdgcn_mfma_f32_16x16x32_f16(al2[mi], bh2[ni], acc[mi][ni], 0, 0, 0);
            }
        __syncthreads();
    }
#undef STAGE

#pragma unroll
    for (int mi = 0; mi < 2; ++mi)
#pragma unroll
        for (int ni = 0; ni < 2; ++ni)
#pragma unroll
            for (int r = 0; r < 4; ++r) {
                int row = m0 + wm + mi * 16 + quad * 4 + r;
                int col = n0 + wn + ni * 16 + lm;
                if (row >= M || col >= Nstore) continue;
                float v = acc[mi][ni][r];
                if (mode == 1) { v += bias[col]; v = (v > 20.f) ? v : log1pf(__expf(v)); }
                else if (mode == 2) v += bias[col] + pos[(size_t)(row % NPATCH) * N + col];
                size_t idx = (size_t)row * N + col;
                if (mode == 3) { atomicAdd(&C[idx], v); continue; }
                if (C) C[idx] = v;
                if (Chi) {
                    _Float16 h = (_Float16)v;
                    Chi[idx] = h;
                    Clo[idx] = (_Float16)(v - (float)h);
                }
            }
}

// ---------------- causal depthwise conv (k=4) + SiLU -> f16 split, 4 elems/thread ----------------
// xz comes as TWO split-K partials (xz[i] + xz[i+XZPS]); also zero-fills projb
__global__ __launch_bounds__(256) void conv_k(
    const float* __restrict__ xz, const float* __restrict__ cw,
    const float* __restrict__ cb, _Float16* __restrict__ xch, _Float16* __restrict__ xcl,
    float* __restrict__ projb)
{
    int i4 = blockIdx.x * 256 + threadIdx.x;
    if (i4 >= M_ROWS * DI / 4) return;
    if (i4 < M_ROWS * 20) ((float4*)projb)[i4] = float4{0.f, 0.f, 0.f, 0.f};
    int e4 = i4 % (DI / 4);
    int m  = i4 / (DI / 4);
    int e  = e4 * 4;
    int l  = m % L_SEQ;
    float4 acc = *(const float4*)&cb[e];
    const float4* cwv = (const float4*)&cw[e * DCONV];   // cwv[j] = taps 0..3 of elem e+j
    float4 c0 = cwv[0], c1 = cwv[1], c2 = cwv[2], c3 = cwv[3];
#pragma unroll
    for (int k = 0; k < DCONV; ++k) {
        int ls = l + k - (DCONV - 1);
        if (ls >= 0) {
            size_t off = (size_t)(m + k - (DCONV - 1)) * (2 * DI) + e;
            float4 v0 = *(const float4*)&xz[off];
            float4 v1 = *(const float4*)&xz[off + XZPS];
            acc.x += (&c0.x)[k] * (v0.x + v1.x);
            acc.y += (&c1.x)[k] * (v0.y + v1.y);
            acc.z += (&c2.x)[k] * (v0.z + v1.z);
            acc.w += (&c3.x)[k] * (v0.w + v1.w);
        }
    }
    float r0 = acc.x / (1.f + __expf(-acc.x));
    float r1 = acc.y / (1.f + __expf(-acc.y));
    float r2 = acc.z / (1.f + __expf(-acc.z));
    float r3 = acc.w / (1.f + __expf(-acc.w));
    _Float16 h0 = (_Float16)r0, h1 = (_Float16)r1, h2 = (_Float16)r2, h3 = (_Float16)r3;
    f16x4 H = {h0, h1, h2, h3};
    f16x4 L = {(_Float16)(r0 - (float)h0), (_Float16)(r1 - (float)h1),
               (_Float16)(r2 - (float)h2), (_Float16)(r3 - (float)h3)};
    ((f16x4*)xch)[i4] = H;
    ((f16x4*)xcl)[i4] = L;
}

// ================= chunked selective scan (2 passes, dt_proj fused) =================
__global__ __launch_bounds__(64) void scanA_k(
    const _Float16* __restrict__ xch, const _Float16* __restrict__ xcl,
    const float* __restrict__ proj, const float* __restrict__ dtw,
    const float* __restrict__ dtb, const float* __restrict__ A_log,
    float* __restrict__ hpart, float* __restrict__ Sdt)
{
    int d = blockIdx.x * 64 + threadIdx.x;
    int b = blockIdx.y, c = blockIdx.z;
    float Aa[DS];
#pragma unroll
    for (int s = 0; s < DS; ++s) Aa[s] = -__expf(A_log[d * DS + s]);
    float W[DTR];
    const float4* Wp = (const float4*)(dtw + (size_t)d * DTR);
#pragma unroll
    for (int i = 0; i < DTR / 4; ++i) {
        float4 w = Wp[i];
        W[4 * i] = w.x; W[4 * i + 1] = w.y; W[4 * i + 2] = w.z; W[4 * i + 3] = w.w;
    }
    float bia = dtb[d];
    float h[DS];
#pragma unroll
    for (int s = 0; s < DS; ++s) h[s] = 0.f;
    float sdt = 0.f;
    size_t base = (size_t)b * L_SEQ + c * LC;
    for (int l = 0; l < LC; ++l) {
        size_t ii = (base + l) * DI + d;
        const float* pr = proj + (base + l) * 80;
        float draw = bia;
#pragma unroll
        for (int r = 0; r < DTR; ++r) draw += pr[r] * W[r];
        float dtv = (draw > 20.f) ? draw : log1pf(__expf(draw));
        float xv  = (float)xch[ii] + (float)xcl[ii];
        float dx = dtv * xv;
        sdt += dtv;
#pragma unroll
        for (int s = 0; s < DS; ++s)
            h[s] = __expf(dtv * Aa[s]) * h[s] + dx * pr[DTR + s];
    }
    size_t o = (size_t)(b * NCH + c) * DS * DI + d;
#pragma unroll
    for (int s = 0; s < DS; ++s) hpart[o + (size_t)s * DI] = h[s];
    Sdt[(size_t)(b * NCH + c) * DI + d] = sdt;
}

// scanC: self-computed chunk prefix, dt_proj fused, emits y (silu-gated, split)
// z-gate read sums the two in_proj split-K partials
__global__ __launch_bounds__(64) void scanC_k(
    const _Float16* __restrict__ xch, const _Float16* __restrict__ xcl,
    const float* __restrict__ proj, const float* __restrict__ xz,
    const float* __restrict__ dtw, const float* __restrict__ dtb,
    const float* __restrict__ A_log, const float* __restrict__ Dp,
    const float* __restrict__ hpart, const float* __restrict__ Sdt,
    _Float16* __restrict__ yh, _Float16* __restrict__ yl)
{
    int d = blockIdx.x * 64 + threadIdx.x;
    int b = blockIdx.y, c = blockIdx.z;
    float Aa[DS];
#pragma unroll
    for (int s = 0; s < DS; ++s) Aa[s] = -__expf(A_log[d * DS + s]);
    float W[DTR];
    const float4* Wp = (const float4*)(dtw + (size_t)d * DTR);
#pragma unroll
    for (int i = 0; i < DTR / 4; ++i) {
        float4 w = Wp[i];
        W[4 * i] = w.x; W[4 * i + 1] = w.y; W[4 * i + 2] = w.z; W[4 * i + 3] = w.w;
    }
    float bia = dtb[d];
    float h[DS];
#pragma unroll
    for (int s = 0; s < DS; ++s) h[s] = 0.f;
    for (int cc = 0; cc < c; ++cc) {
        float sdt = Sdt[(size_t)(b * NCH + cc) * DI + d];
        size_t o = (size_t)(b * NCH + cc) * DS * DI + d;
#pragma unroll
        for (int s = 0; s < DS; ++s)
            h[s] = __expf(Aa[s] * sdt) * h[s] + hpart[o + (size_t)s * DI];
    }
    float dP = Dp[d];
    size_t base = (size_t)b * L_SEQ + c * LC;
    for (int l = 0; l < LC; ++l) {
        size_t ii = (base + l) * DI + d;
        const float* pr = proj + (base + l) * 80;
        float draw = bia;
#pragma unroll
        for (int r = 0; r < DTR; ++r) draw += pr[r] * W[r];
        float dtv = (draw > 20.f) ? draw : log1pf(__expf(draw));
        float xv  = (float)xch[ii] + (float)xcl[ii];
        size_t iz = (base + l) * 2 * DI + DI + d;
        float zv  = xz[iz] + xz[iz + XZPS];
        float dx = dtv * xv;
        float accv = 0.f;
#pragma unroll
        for (int s = 0; s < DS; ++s) {
            h[s] = __expf(dtv * Aa[s]) * h[s] + dx * pr[DTR + s];
            accv += h[s] * pr[DTR + DS + s];
        }
        float yv = accv + xv * dP;
        float sg = 1.f / (1.f + __expf(-zv));
        float vy = yv * (zv * sg);
        _Float16 hh = (_Float16)vy;
        yh[ii] = hh;
        yl[ii] = (_Float16)(vy - (float)hh);
    }
}

// ---------------- sum 4 split-K partials -> f16 hi/lo split ----------------
__global__ __launch_bounds__(256) void red4split_k(const float* __restrict__ part,
    _Float16* __restrict__ hi, _Float16* __restrict__ lo, int n4, int stride4)
{
    int i = blockIdx.x * 256 + threadIdx.x;
    if (i >= n4) return;
    const float4* p = (const float4*)part;
    float4 a = p[i], b = p[i + stride4], c = p[i + 2 * stride4], e = p[i + 3 * stride4];
    float x0 = a.x + b.x + c.x + e.x;
    float x1 = a.y + b.y + c.y + e.y;
    float x2 = a.z + b.z + c.z + e.z;
    float x3 = a.w + b.w + c.w + e.w;
    _Float16 h0 = (_Float16)x0, h1 = (_Float16)x1, h2 = (_Float16)x2, h3 = (_Float16)x3;
    f16x4 H = {h0, h1, h2, h3};
    f16x4 L = {(_Float16)(x0 - (float)h0), (_Float16)(x1 - (float)h1),
               (_Float16)(x2 - (float)h2), (_Float16)(x3 - (float)h3)};
    ((f16x4*)hi)[i] = H;
    ((f16x4*)lo)[i] = L;
}

// ---------------- layernorm over D=768 from f16 hi+lo ----------------
__global__ __launch_bounds__(256) void ln_k(const _Float16* __restrict__ hh,
    const _Float16* __restrict__ hl,
    const float* __restrict__ w, const float* __restrict__ bias, float* __restrict__ out)
{
    int row = blockIdx.x;
    int tid = threadIdx.x;
    size_t base = (size_t)row * DD;
    float v0 = (float)hh[base + tid]       + (float)hl[base + tid];
    float v1 = (float)hh[base + tid + 256] + (float)hl[base + tid + 256];
    float v2 = (float)hh[base + tid + 512] + (float)hl[base + tid + 512];
    float s = v0 + v1 + v2;
    __shared__ float red[4];
    for (int off = 32; off; off >>= 1) s += __shfl_down(s, off);
    if ((tid & 63) == 0) red[tid >> 6] = s;
    __syncthreads();
    float mu = (red[0] + red[1] + red[2] + red[3]) * (1.f / 768.f);
    __syncthreads();
    float d0 = v0 - mu, d1 = v1 - mu, d2 = v2 - mu;
    float vs = d0 * d0 + d1 * d1 + d2 * d2;
    for (int off = 32; off; off >>= 1) vs += __shfl_down(vs, off);
    if ((tid & 63) == 0) red[tid >> 6] = vs;
    __syncthreads();
    float var = (red[0] + red[1] + red[2] + red[3]) * (1.f / 768.f);
    float rs = rsqrtf(var + 1e-5f);
    out[base + tid]       = d0 * rs * w[tid]       + bias[tid];
    out[base + tid + 256] = d1 * rs * w[tid + 256] + bias[tid + 256];
    out[base + tid + 512] = d2 * rs * w[tid + 512] + bias[tid + 512];
}

extern "C" void kernel_launch(void* const* d_in, const int* in_sizes, int n_in,
                              void* d_out, int out_size, void* d_ws, size_t ws_size,
                              hipStream_t stream) {
    const float* x        = (const float*)d_in[0];
    const float* patch_w  = (const float*)d_in[1];
    const float* patch_b  = (const float*)d_in[2];
    const float* pos      = (const float*)d_in[3];
    const float* in_proj  = (const float*)d_in[4];
    const float* conv_w   = (const float*)d_in[5];
    const float* conv_b   = (const float*)d_in[6];
    const float* x_proj   = (const float*)d_in[7];
    const float* dt_w     = (const float*)d_in[8];
    const float* dt_b     = (const float*)d_in[9];
    const float* A_log    = (const float*)d_in[10];
    const float* D_param  = (const float*)d_in[11];
    const float* out_w    = (const float*)d_in[12];
    const float* norm_w   = (const float*)d_in[13];
    const float* norm_b   = (const float*)d_in[14];
    float* out = (float*)d_out;

    // fp32 workspace
    float* ws    = (float*)d_ws;
    float* xzb   = ws;                      // 2 x 4,816,896 (in_proj split-K=2 partials)
    float* projb = xzb   + 2 * XZPS;        //   125,440
    float* hpart = projb + 125440;          // 2,555,904 (8*13*16*1536)
    float* sdtb  = hpart + 2555904;         //   159,744 (8*13*1536)
    float* opart = sdtb  + 159744;          // 4,816,896 (4 x 1568*768 split-K partials)
    // f16 workspace (A-operand buffers padded to MPAD=1664 rows)
    _Float16* fp  = (_Float16*)(opart + 4816896);
    _Float16* hbh = fp;                     // 1664*768
    _Float16* hbl = hbh + MPAD * DD;
    _Float16* yh  = hbl + MPAD * DD;        // 1664*1536 (also im2col out)
    _Float16* yl  = yh  + MPAD * DI;
    _Float16* xch = yl  + MPAD * DI;        // 1664*1536
    _Float16* xcl = xch + MPAD * DI;
    _Float16* pwh = xcl + MPAD * DI;        // 768*768
    _Float16* pwl = pwh + 589824;
    // all-layer weight splits (in/out proj: hi-plane only, 2-term GEMM)
    _Float16* wih = pwl + 589824;           // 12 * 3072*768
    _Float16* woh = wih + (size_t)NLAY * 2359296;   // 12 * 768*1536
    _Float16* xwh = woh + (size_t)NLAY * 1179648;   // 12 * 128*1536 (row-padded)
    _Float16* xwl = xwh + (size_t)NLAY * 196608;

    // ---- weight splits, batched over layers ----
    split4hi_k<<<(NLAY * 2359296 / 4 + 255) / 256, 256, 0, stream>>>(in_proj, wih, NLAY * 2359296 / 4);
    split4hi_k<<<(NLAY * 1179648 / 4 + 255) / 256, 256, 0, stream>>>(out_w, woh, NLAY * 1179648 / 4);
    splitpadN_k<<<(NLAY * 196608 + 255) / 256, 256, 0, stream>>>(
        x_proj, xwh, xwl, 80 * DI, 80, DI, DI, 196608, NLAY * 196608);
    split4_k<<<(589824 / 4 + 255) / 256, 256, 0, stream>>>(patch_w, pwh, pwl, 589824 / 4);

    // ---- patch embed ----
    im2col_k<<<(M_ROWS * DD + 255) / 256, 256, 0, stream>>>(x, yh, yl);
    mgemm_k<<<dim3(12, 25), 256, 0, stream>>>(yh, yl, pwh, pwl,
        nullptr, hbh, hbl, M_ROWS, DD, DD, DD, DD, patch_b, pos, 2);

    for (int l = 0; l < NLAY; ++l) {
        const float* Al  = A_log + (size_t)l * DI * DS;
        const float* Wdt = dt_w  + (size_t)l * DI * DTR;
        const float* Bdt = dt_b  + (size_t)l * DI;
        // in_proj: (1568,768) x (3072,768)^T -> 2 split-K partials (128x128 BK=64 kernel)
        mgemm128_k<<<dim3(24, 13, 2), 256, 0, stream>>>(hbh, hbl,
            wih + (size_t)l * 2359296,
            xzb, M_ROWS, 2 * DI, DD, DD, (long)XZPS);
        // conv + silu (sums the 2 partials) -> xc split; also zeroes projb
        conv_k<<<(M_ROWS * DI / 4) / 256, 256, 0, stream>>>(xzb, conv_w + (size_t)l * DI * DCONV,
                                                            conv_b + (size_t)l * DI, xch, xcl, projb);
        // x_proj: split-K=4 atomic -> projb fp32 (f16x3 precision)
        mgemm_k<<<dim3(2, 25, 4), 256, 0, stream>>>(xch, xcl,
            xwh + (size_t)l * 196608, xwl + (size_t)l * 196608,
            projb, nullptr, nullptr, M_ROWS, 80, DI, DI, 80, nullptr, nullptr, 3);
        // chunked scan, dt_proj fused in (fp32 dot), scanB absorbed into scanC prefix
        scanA_k<<<dim3(DI / 64, BB, NCH), 64, 0, stream>>>(xch, xcl, projb, Wdt, Bdt, Al, hpart, sdtb);
        scanC_k<<<dim3(DI / 64, BB, NC), 64, 0, stream>>>(xch, xcl, projb, xzb, Wdt, Bdt, Al,
                                                          D_param + (size_t)l * DI, hpart, sdtb, yh, yl);
        // out_proj: 128x128 BK=64 2-term split-K=4 -> 4 partial buffers, then reduce+split
        mgemm128_k<<<dim3(6, 13, 4), 256, 0, stream>>>(yh, yl,
            woh + (size_t)l * 1179648,
            opart, M_ROWS, DD, DI, DI, (long)M_ROWS * DD);
        red4split_k<<<(M_ROWS * DD / 4 + 255) / 256, 256, 0, stream>>>(
            opart, hbh, hbl, M_ROWS * DD / 4, M_ROWS * DD / 4);
    }

    ln_k<<<M_ROWS, 256, 0, stream>>>(hbh, hbl, norm_w, norm_b, out);
}

// Round 9
// 1758.361 us; speedup vs baseline: 1.2205x; 1.0662x over previous
//
#include <hip/hip_runtime.h>

#define BB 8
#define IMG 224
#define DD 768
#define NLAY 12
#define DI 1536
#define DS 16
#define DTR 48
#define NPATCH 196
#define L_SEQ 196
#define M_ROWS 1568   // BB*NPATCH
#define MPAD 1664     // 13*128 row padding for A operands
#define DCONV 4
#define NC 14
#define LC 14
#define NCH 13        // stored chunk states (last chunk's partial is never consumed)
#define XZPS 4816896  // in_proj split-K partial stride (M_ROWS*2*DI floats)

typedef _Float16 f16x8 __attribute__((ext_vector_type(8)));
typedef _Float16 f16x4 __attribute__((ext_vector_type(4)));
typedef float f32x4 __attribute__((ext_vector_type(4)));

__device__ __forceinline__ void gll16(const void* g, void* l) {
    __builtin_amdgcn_global_load_lds(
        (const __attribute__((address_space(1))) unsigned int*)g,
        (__attribute__((address_space(3))) unsigned int*)l,
        16, 0, 0);
}

// ---------------- split fp32 -> (hi,lo) f16, 4 elems/thread ----------------
__global__ __launch_bounds__(256) void split4_k(const float* __restrict__ in,
    _Float16* __restrict__ hi, _Float16* __restrict__ lo, int n4)
{
    int i = blockIdx.x * 256 + threadIdx.x;
    if (i >= n4) return;
    float4 v = ((const float4*)in)[i];
    _Float16 h0 = (_Float16)v.x, h1 = (_Float16)v.y, h2 = (_Float16)v.z, h3 = (_Float16)v.w;
    f16x4 H = {h0, h1, h2, h3};
    f16x4 L = {(_Float16)(v.x - (float)h0), (_Float16)(v.y - (float)h1),
               (_Float16)(v.z - (float)h2), (_Float16)(v.w - (float)h3)};
    ((f16x4*)hi)[i] = H;
    ((f16x4*)lo)[i] = L;
}

// ---------------- fp32 -> f16 hi only (weights for 2-term GEMMs) ----------------
__global__ __launch_bounds__(256) void split4hi_k(const float* __restrict__ in,
    _Float16* __restrict__ hi, int n4)
{
    int i = blockIdx.x * 256 + threadIdx.x;
    if (i >= n4) return;
    float4 v = ((const float4*)in)[i];
    f16x4 H = {(_Float16)v.x, (_Float16)v.y, (_Float16)v.z, (_Float16)v.w};
    ((f16x4*)hi)[i] = H;
}

// ---------------- layer-batched split with zero padding ----------------
__global__ __launch_bounds__(256) void splitpadN_k(const float* __restrict__ in,
    _Float16* __restrict__ hi, _Float16* __restrict__ lo,
    int perIn, int inRows, int inCols, int outLd, int perOut, int total)
{
    int i = blockIdx.x * 256 + threadIdx.x;
    if (i >= total) return;
    int l = i / perOut, j = i % perOut;
    int r = j / outLd, c = j % outLd;
    float v = (r < inRows && c < inCols) ? in[(size_t)l * perIn + r * inCols + c] : 0.f;
    _Float16 h = (_Float16)v;
    hi[i] = h;
    lo[i] = (_Float16)(v - (float)h);
}

// ---------------- im2col with split output ----------------
__global__ __launch_bounds__(256) void im2col_k(const float* __restrict__ x,
    _Float16* __restrict__ hi, _Float16* __restrict__ lo)
{
    int idx = blockIdx.x * 256 + threadIdx.x;
    if (idx >= M_ROWS * DD) return;
    int k = idx % DD;
    int m = idx / DD;
    int b = m / NPATCH;
    int t = m % NPATCH;
    int i = t / 14, j = t % 14;
    int c = k / 256;
    int pq = k % 256;
    int p = pq / 16, q = pq % 16;
    float v = x[(((size_t)b * 3 + c) * IMG + i * 16 + p) * IMG + j * 16 + q];
    _Float16 h = (_Float16)v;
    hi[idx] = h;
    lo[idx] = (_Float16)(v - (float)h);
}

// ---------------- pure-f16 MFMA GEMM, 128x128, BK=64: Ah x Bh^T ----------------
// C[M,N] (fp32) = Ah[M,K(lda)] * Bh[N,K]^T. A padded to 128-multiple rows.
// gridDim.z>1: split-K, each z writes its own partial buffer C + z*partStride.
__global__ __launch_bounds__(256) void mgemm128f_k(
    const _Float16* __restrict__ Ah, const _Float16* __restrict__ Bh,
    float* __restrict__ C, int M, int N, int K, int lda, long partStride)
{
    __shared__ __align__(16) _Float16 As[128][64];   // [row][k], seg-swizzled
    __shared__ __align__(16) _Float16 Bs[128][64];
    int tid = threadIdx.x, lane = tid & 63, wid = tid >> 6;
    int m0 = blockIdx.y * 128, n0 = blockIdx.x * 128;
    int kBeg = 0, nIter = K / 64;
    if (gridDim.z > 1) {
        int kPer = K / gridDim.z;
        kBeg = blockIdx.z * kPer;
        nIter = kPer / 64;
        C += (size_t)blockIdx.z * partStride;
    }

    // staging: wave covers rows [r0, r0+32); per gll16 call: 8 rows x 8 segs of 16B.
    int r0 = wid * 32;
    int lr = lane >> 3;
    int qs = ((lane & 7) ^ lr) * 8;                  // swizzled global k-seg
    const _Float16* AhP = Ah + (size_t)(m0 + r0 + lr) * lda + kBeg + qs;
    const _Float16* BhP = Bh + (size_t)(n0 + r0 + lr) * K + kBeg + qs;
    size_t a8 = (size_t)8 * lda, b8 = (size_t)8 * K;

    int wm = (wid >> 1) * 64, wn = (wid & 1) * 64;
    int lm = lane & 15, quad = lane >> 4;
    int seg0 = (quad ^ (lm & 7)) * 8;                // read-side swizzle, k-chunk 0
    f32x4 acc[4][4] = {};

    for (int it = 0; it < nIter; ++it) {
        int k0 = it * 64;
#pragma unroll
        for (int j = 0; j < 4; ++j) {
            gll16(AhP + (size_t)j * a8 + k0, &As[r0 + 8 * j][0]);
            gll16(BhP + (size_t)j * b8 + k0, &Bs[r0 + 8 * j][0]);
        }
        __syncthreads();

#pragma unroll
        for (int ch = 0; ch < 2; ++ch) {
            int ls = seg0 ^ (ch * 32);
            f16x8 ah[4], bh4[4];
#pragma unroll
            for (int i = 0; i < 4; ++i) {
                ah[i]  = *(const f16x8*)&As[wm + i * 16 + lm][ls];
                bh4[i] = *(const f16x8*)&Bs[wn + i * 16 + lm][ls];
            }
#pragma unroll
            for (int mi = 0; mi < 4; ++mi)
#pragma unroll
                for (int ni = 0; ni < 4; ++ni)
                    acc[mi][ni] = __builtin_amdgcn_mfma_f32_16x16x32_f16(ah[mi], bh4[ni], acc[mi][ni], 0, 0, 0);
        }
        __syncthreads();
    }

#pragma unroll
    for (int mi = 0; mi < 4; ++mi)
#pragma unroll
        for (int ni = 0; ni < 4; ++ni)
#pragma unroll
            for (int r = 0; r < 4; ++r) {
                int row = m0 + wm + mi * 16 + quad * 4 + r;
                int col = n0 + wn + ni * 16 + lm;
                if (row < M) C[(size_t)row * N + col] = acc[mi][ni][r];
            }
}

// ---------------- f16x3 MFMA GEMM, 64x64x32, dbuf, swizzled ----------------
// mode 1: softplus(v+bias[n])  2: v+bias[n]+pos[(m%196)*N+n]  3: atomicAdd (split-K grid.z)
__global__ __launch_bounds__(256) void mgemm_k(
    const _Float16* __restrict__ Ah, const _Float16* __restrict__ Al,
    const _Float16* __restrict__ Bh, const _Float16* __restrict__ Bl,
    float* __restrict__ C, _Float16* __restrict__ Chi, _Float16* __restrict__ Clo,
    int M, int N, int K, int lda, int Nstore,
    const float* __restrict__ bias, const float* __restrict__ pos, int mode)
{
    __shared__ __align__(16) _Float16 As[2][2][64][32];
    __shared__ __align__(16) _Float16 Bs[2][2][64][32];
    int tid = threadIdx.x, lane = tid & 63, wid = tid >> 6;
    int m0 = blockIdx.y * 64, n0 = blockIdx.x * 64;
    int kBeg = 0, nIter = K / 32;
    if (gridDim.z > 1) { int kPer = K / gridDim.z; kBeg = blockIdx.z * kPer; nIter = kPer / 32; }

    int srow = wid * 16 + (lane >> 2);
    int qs = ((lane & 3) ^ ((lane >> 3) & 3)) * 8;
    const _Float16* aH = Ah + (size_t)(m0 + srow) * lda + kBeg + qs;
    const _Float16* aL = Al + (size_t)(m0 + srow) * lda + kBeg + qs;
    const _Float16* bH = Bh + (size_t)(n0 + srow) * K + kBeg + qs;
    const _Float16* bL = Bl + (size_t)(n0 + srow) * K + kBeg + qs;

#define STAGE(buf, it) { int ko = (it) * 32;              \
        gll16(aH + ko, &As[buf][0][wid * 16][0]);          \
        gll16(aL + ko, &As[buf][1][wid * 16][0]);          \
        gll16(bH + ko, &Bs[buf][0][wid * 16][0]);          \
        gll16(bL + ko, &Bs[buf][1][wid * 16][0]); }

    int wm = (wid >> 1) * 32, wn = (wid & 1) * 32;
    int lm = lane & 15, quad = lane >> 4;
    int segA = (quad ^ ((lm >> 1) & 3)) * 8;
    f32x4 acc[2][2] = {};

    STAGE(0, 0);
    for (int it = 0; it < nIter; ++it) {
        int buf = it & 1;
        if (it + 1 < nIter) STAGE(buf ^ 1, it + 1);
        __syncthreads();
        f16x8 ah[2], al2[2], bh2[2], bl2[2];
#pragma unroll
        for (int i = 0; i < 2; ++i) {
            ah[i]  = *(const f16x8*)&As[buf][0][wm + i * 16 + lm][segA];
            al2[i] = *(const f16x8*)&As[buf][1][wm + i * 16 + lm][segA];
            bh2[i] = *(const f16x8*)&Bs[buf][0][wn + i * 16 + lm][segA];
            bl2[i] = *(const f16x8*)&Bs[buf][1][wn + i * 16 + lm][segA];
        }
#pragma unroll
        for (int mi = 0; mi < 2; ++mi)
#pragma unroll
            for (int ni = 0; ni < 2; ++ni) {
                acc[mi][ni] = __builtin_amdgcn_mfma_f32_16x16x32_f16(ah[mi],  bh2[ni], acc[mi][ni], 0, 0, 0);
                acc[mi][ni] = __builtin_amdgcn_mfma_f32_16x16x32_f16(ah[mi],  bl2[ni], acc[mi][ni], 0, 0, 0);
                acc[mi][ni] = __builtin_amdgcn_mfma_f32_16x16x32_f16(al2[mi], bh2[ni], acc[mi][ni], 0, 0, 0);
            }
        __syncthreads();
    }
#undef STAGE

#pragma unroll
    for (int mi = 0; mi < 2; ++mi)
#pragma unroll
        for (int ni = 0; ni < 2; ++ni)
#pragma unroll
            for (int r = 0; r < 4; ++r) {
                int row = m0 + wm + mi * 16 + quad * 4 + r;
                int col = n0 + wn + ni * 16 + lm;
                if (row >= M || col >= Nstore) continue;
                float v = acc[mi][ni][r];
                if (mode == 1) { v += bias[col]; v = (v > 20.f) ? v : log1pf(__expf(v)); }
                else if (mode == 2) v += bias[col] + pos[(size_t)(row % NPATCH) * N + col];
                size_t idx = (size_t)row * N + col;
                if (mode == 3) { atomicAdd(&C[idx], v); continue; }
                if (C) C[idx] = v;
                if (Chi) {
                    _Float16 h = (_Float16)v;
                    Chi[idx] = h;
                    if (Clo) Clo[idx] = (_Float16)(v - (float)h);
                }
            }
}

// ---------------- causal depthwise conv (k=4) + SiLU -> f16 split, 4 elems/thread ----------------
// xz comes as TWO split-K partials (xz[i] + xz[i+XZPS]); also zero-fills projb
__global__ __launch_bounds__(256) void conv_k(
    const float* __restrict__ xz, const float* __restrict__ cw,
    const float* __restrict__ cb, _Float16* __restrict__ xch, _Float16* __restrict__ xcl,
    float* __restrict__ projb)
{
    int i4 = blockIdx.x * 256 + threadIdx.x;
    if (i4 >= M_ROWS * DI / 4) return;
    if (i4 < M_ROWS * 20) ((float4*)projb)[i4] = float4{0.f, 0.f, 0.f, 0.f};
    int e4 = i4 % (DI / 4);
    int m  = i4 / (DI / 4);
    int e  = e4 * 4;
    int l  = m % L_SEQ;
    float4 acc = *(const float4*)&cb[e];
    const float4* cwv = (const float4*)&cw[e * DCONV];   // cwv[j] = taps 0..3 of elem e+j
    float4 c0 = cwv[0], c1 = cwv[1], c2 = cwv[2], c3 = cwv[3];
#pragma unroll
    for (int k = 0; k < DCONV; ++k) {
        int ls = l + k - (DCONV - 1);
        if (ls >= 0) {
            size_t off = (size_t)(m + k - (DCONV - 1)) * (2 * DI) + e;
            float4 v0 = *(const float4*)&xz[off];
            float4 v1 = *(const float4*)&xz[off + XZPS];
            acc.x += (&c0.x)[k] * (v0.x + v1.x);
            acc.y += (&c1.x)[k] * (v0.y + v1.y);
            acc.z += (&c2.x)[k] * (v0.z + v1.z);
            acc.w += (&c3.x)[k] * (v0.w + v1.w);
        }
    }
    float r0 = acc.x / (1.f + __expf(-acc.x));
    float r1 = acc.y / (1.f + __expf(-acc.y));
    float r2 = acc.z / (1.f + __expf(-acc.z));
    float r3 = acc.w / (1.f + __expf(-acc.w));
    _Float16 h0 = (_Float16)r0, h1 = (_Float16)r1, h2 = (_Float16)r2, h3 = (_Float16)r3;
    f16x4 H = {h0, h1, h2, h3};
    f16x4 L = {(_Float16)(r0 - (float)h0), (_Float16)(r1 - (float)h1),
               (_Float16)(r2 - (float)h2), (_Float16)(r3 - (float)h3)};
    ((f16x4*)xch)[i4] = H;
    ((f16x4*)xcl)[i4] = L;
}

// ================= chunked selective scan (2 passes, dt_proj fused) =================
__global__ __launch_bounds__(64) void scanA_k(
    const _Float16* __restrict__ xch, const _Float16* __restrict__ xcl,
    const float* __restrict__ proj, const float* __restrict__ dtw,
    const float* __restrict__ dtb, const float* __restrict__ A_log,
    float* __restrict__ hpart, float* __restrict__ Sdt)
{
    int d = blockIdx.x * 64 + threadIdx.x;
    int b = blockIdx.y, c = blockIdx.z;
    float Aa[DS];
#pragma unroll
    for (int s = 0; s < DS; ++s) Aa[s] = -__expf(A_log[d * DS + s]);
    float W[DTR];
    const float4* Wp = (const float4*)(dtw + (size_t)d * DTR);
#pragma unroll
    for (int i = 0; i < DTR / 4; ++i) {
        float4 w = Wp[i];
        W[4 * i] = w.x; W[4 * i + 1] = w.y; W[4 * i + 2] = w.z; W[4 * i + 3] = w.w;
    }
    float bia = dtb[d];
    float h[DS];
#pragma unroll
    for (int s = 0; s < DS; ++s) h[s] = 0.f;
    float sdt = 0.f;
    size_t base = (size_t)b * L_SEQ + c * LC;
    for (int l = 0; l < LC; ++l) {
        size_t ii = (base + l) * DI + d;
        const float* pr = proj + (base + l) * 80;
        float draw = bia;
#pragma unroll
        for (int r = 0; r < DTR; ++r) draw += pr[r] * W[r];
        float dtv = (draw > 20.f) ? draw : log1pf(__expf(draw));
        float xv  = (float)xch[ii] + (float)xcl[ii];
        float dx = dtv * xv;
        sdt += dtv;
#pragma unroll
        for (int s = 0; s < DS; ++s)
            h[s] = __expf(dtv * Aa[s]) * h[s] + dx * pr[DTR + s];
    }
    size_t o = (size_t)(b * NCH + c) * DS * DI + d;
#pragma unroll
    for (int s = 0; s < DS; ++s) hpart[o + (size_t)s * DI] = h[s];
    Sdt[(size_t)(b * NCH + c) * DI + d] = sdt;
}

// scanC: self-computed chunk prefix, dt_proj fused, emits y (silu-gated, f16 hi only)
// z-gate read sums the two in_proj split-K partials
__global__ __launch_bounds__(64) void scanC_k(
    const _Float16* __restrict__ xch, const _Float16* __restrict__ xcl,
    const float* __restrict__ proj, const float* __restrict__ xz,
    const float* __restrict__ dtw, const float* __restrict__ dtb,
    const float* __restrict__ A_log, const float* __restrict__ Dp,
    const float* __restrict__ hpart, const float* __restrict__ Sdt,
    _Float16* __restrict__ yh)
{
    int d = blockIdx.x * 64 + threadIdx.x;
    int b = blockIdx.y, c = blockIdx.z;
    float Aa[DS];
#pragma unroll
    for (int s = 0; s < DS; ++s) Aa[s] = -__expf(A_log[d * DS + s]);
    float W[DTR];
    const float4* Wp = (const float4*)(dtw + (size_t)d * DTR);
#pragma unroll
    for (int i = 0; i < DTR / 4; ++i) {
        float4 w = Wp[i];
        W[4 * i] = w.x; W[4 * i + 1] = w.y; W[4 * i + 2] = w.z; W[4 * i + 3] = w.w;
    }
    float bia = dtb[d];
    float h[DS];
#pragma unroll
    for (int s = 0; s < DS; ++s) h[s] = 0.f;
    for (int cc = 0; cc < c; ++cc) {
        float sdt = Sdt[(size_t)(b * NCH + cc) * DI + d];
        size_t o = (size_t)(b * NCH + cc) * DS * DI + d;
#pragma unroll
        for (int s = 0; s < DS; ++s)
            h[s] = __expf(Aa[s] * sdt) * h[s] + hpart[o + (size_t)s * DI];
    }
    float dP = Dp[d];
    size_t base = (size_t)b * L_SEQ + c * LC;
    for (int l = 0; l < LC; ++l) {
        size_t ii = (base + l) * DI + d;
        const float* pr = proj + (base + l) * 80;
        float draw = bia;
#pragma unroll
        for (int r = 0; r < DTR; ++r) draw += pr[r] * W[r];
        float dtv = (draw > 20.f) ? draw : log1pf(__expf(draw));
        float xv  = (float)xch[ii] + (float)xcl[ii];
        size_t iz = (base + l) * 2 * DI + DI + d;
        float zv  = xz[iz] + xz[iz + XZPS];
        float dx = dtv * xv;
        float accv = 0.f;
#pragma unroll
        for (int s = 0; s < DS; ++s) {
            h[s] = __expf(dtv * Aa[s]) * h[s] + dx * pr[DTR + s];
            accv += h[s] * pr[DTR + DS + s];
        }
        float yv = accv + xv * dP;
        float sg = 1.f / (1.f + __expf(-zv));
        yh[ii] = (_Float16)(yv * (zv * sg));
    }
}

// ---------------- sum 4 split-K partials -> f16 hi only ----------------
__global__ __launch_bounds__(256) void red4hi_k(const float* __restrict__ part,
    _Float16* __restrict__ hi, int n4, int stride4)
{
    int i = blockIdx.x * 256 + threadIdx.x;
    if (i >= n4) return;
    const float4* p = (const float4*)part;
    float4 a = p[i], b = p[i + stride4], c = p[i + 2 * stride4], e = p[i + 3 * stride4];
    f16x4 H = {(_Float16)(a.x + b.x + c.x + e.x), (_Float16)(a.y + b.y + c.y + e.y),
               (_Float16)(a.z + b.z + c.z + e.z), (_Float16)(a.w + b.w + c.w + e.w)};
    ((f16x4*)hi)[i] = H;
}

// ---------------- layernorm over D=768 from f16 hi ----------------
__global__ __launch_bounds__(256) void ln_k(const _Float16* __restrict__ hh,
    const float* __restrict__ w, const float* __restrict__ bias, float* __restrict__ out)
{
    int row = blockIdx.x;
    int tid = threadIdx.x;
    size_t base = (size_t)row * DD;
    float v0 = (float)hh[base + tid];
    float v1 = (float)hh[base + tid + 256];
    float v2 = (float)hh[base + tid + 512];
    float s = v0 + v1 + v2;
    __shared__ float red[4];
    for (int off = 32; off; off >>= 1) s += __shfl_down(s, off);
    if ((tid & 63) == 0) red[tid >> 6] = s;
    __syncthreads();
    float mu = (red[0] + red[1] + red[2] + red[3]) * (1.f / 768.f);
    __syncthreads();
    float d0 = v0 - mu, d1 = v1 - mu, d2 = v2 - mu;
    float vs = d0 * d0 + d1 * d1 + d2 * d2;
    for (int off = 32; off; off >>= 1) vs += __shfl_down(vs, off);
    if ((tid & 63) == 0) red[tid >> 6] = vs;
    __syncthreads();
    float var = (red[0] + red[1] + red[2] + red[3]) * (1.f / 768.f);
    float rs = rsqrtf(var + 1e-5f);
    out[base + tid]       = d0 * rs * w[tid]       + bias[tid];
    out[base + tid + 256] = d1 * rs * w[tid + 256] + bias[tid + 256];
    out[base + tid + 512] = d2 * rs * w[tid + 512] + bias[tid + 512];
}

extern "C" void kernel_launch(void* const* d_in, const int* in_sizes, int n_in,
                              void* d_out, int out_size, void* d_ws, size_t ws_size,
                              hipStream_t stream) {
    const float* x        = (const float*)d_in[0];
    const float* patch_w  = (const float*)d_in[1];
    const float* patch_b  = (const float*)d_in[2];
    const float* pos      = (const float*)d_in[3];
    const float* in_proj  = (const float*)d_in[4];
    const float* conv_w   = (const float*)d_in[5];
    const float* conv_b   = (const float*)d_in[6];
    const float* x_proj   = (const float*)d_in[7];
    const float* dt_w     = (const float*)d_in[8];
    const float* dt_b     = (const float*)d_in[9];
    const float* A_log    = (const float*)d_in[10];
    const float* D_param  = (const float*)d_in[11];
    const float* out_w    = (const float*)d_in[12];
    const float* norm_w   = (const float*)d_in[13];
    const float* norm_b   = (const float*)d_in[14];
    float* out = (float*)d_out;

    // fp32 workspace
    float* ws    = (float*)d_ws;
    float* xzb   = ws;                      // 2 x 4,816,896 (in_proj split-K=2 partials)
    float* projb = xzb   + 2 * XZPS;        //   125,440
    float* hpart = projb + 125440;          // 2,555,904 (8*13*16*1536)
    float* sdtb  = hpart + 2555904;         //   159,744 (8*13*1536)
    float* opart = sdtb  + 159744;          // 4,816,896 (4 x 1568*768 split-K partials)
    // f16 workspace (A-operand buffers padded to MPAD=1664 rows)
    _Float16* fp  = (_Float16*)(opart + 4816896);
    _Float16* hbh = fp;                     // 1664*768 (h, f16 hi only)
    _Float16* hbl = hbh + MPAD * DD;        // unused (layout keep)
    _Float16* yh  = hbl + MPAD * DD;        // 1664*1536 (y, f16 hi only; also im2col out hi)
    _Float16* yl  = yh  + MPAD * DI;        // im2col lo (patch embed only)
    _Float16* xch = yl  + MPAD * DI;        // 1664*1536
    _Float16* xcl = xch + MPAD * DI;
    _Float16* pwh = xcl + MPAD * DI;        // 768*768
    _Float16* pwl = pwh + 589824;
    // all-layer weight splits (in/out proj: hi-plane only, pure-f16 GEMM)
    _Float16* wih = pwl + 589824;           // 12 * 3072*768
    _Float16* woh = wih + (size_t)NLAY * 2359296;   // 12 * 768*1536
    _Float16* xwh = woh + (size_t)NLAY * 1179648;   // 12 * 128*1536 (row-padded)
    _Float16* xwl = xwh + (size_t)NLAY * 196608;

    // ---- weight splits, batched over layers ----
    split4hi_k<<<(NLAY * 2359296 / 4 + 255) / 256, 256, 0, stream>>>(in_proj, wih, NLAY * 2359296 / 4);
    split4hi_k<<<(NLAY * 1179648 / 4 + 255) / 256, 256, 0, stream>>>(out_w, woh, NLAY * 1179648 / 4);
    splitpadN_k<<<(NLAY * 196608 + 255) / 256, 256, 0, stream>>>(
        x_proj, xwh, xwl, 80 * DI, 80, DI, DI, 196608, NLAY * 196608);
    split4_k<<<(589824 / 4 + 255) / 256, 256, 0, stream>>>(patch_w, pwh, pwl, 589824 / 4);

    // ---- patch embed (f16x3, h stored hi-only) ----
    im2col_k<<<(M_ROWS * DD + 255) / 256, 256, 0, stream>>>(x, yh, yl);
    mgemm_k<<<dim3(12, 25), 256, 0, stream>>>(yh, yl, pwh, pwl,
        nullptr, hbh, nullptr, M_ROWS, DD, DD, DD, DD, patch_b, pos, 2);

    for (int l = 0; l < NLAY; ++l) {
        const float* Al  = A_log + (size_t)l * DI * DS;
        const float* Wdt = dt_w  + (size_t)l * DI * DTR;
        const float* Bdt = dt_b  + (size_t)l * DI;
        // in_proj: h(f16) x W(f16)^T -> 2 split-K partials (pure-f16 128x128 BK=64)
        mgemm128f_k<<<dim3(24, 13, 2), 256, 0, stream>>>(hbh,
            wih + (size_t)l * 2359296,
            xzb, M_ROWS, 2 * DI, DD, DD, (long)XZPS);
        // conv + silu (sums the 2 partials) -> xc split (hi+lo kept); also zeroes projb
        conv_k<<<(M_ROWS * DI / 4) / 256, 256, 0, stream>>>(xzb, conv_w + (size_t)l * DI * DCONV,
                                                            conv_b + (size_t)l * DI, xch, xcl, projb);
        // x_proj: split-K=4 atomic -> projb fp32 (f16x3 precision on scan-critical path)
        mgemm_k<<<dim3(2, 25, 4), 256, 0, stream>>>(xch, xcl,
            xwh + (size_t)l * 196608, xwl + (size_t)l * 196608,
            projb, nullptr, nullptr, M_ROWS, 80, DI, DI, 80, nullptr, nullptr, 3);
        // chunked scan, dt_proj fused in (fp32 dot), scanB absorbed into scanC prefix
        scanA_k<<<dim3(DI / 64, BB, NCH), 64, 0, stream>>>(xch, xcl, projb, Wdt, Bdt, Al, hpart, sdtb);
        scanC_k<<<dim3(DI / 64, BB, NC), 64, 0, stream>>>(xch, xcl, projb, xzb, Wdt, Bdt, Al,
                                                          D_param + (size_t)l * DI, hpart, sdtb, yh);
        // out_proj: y(f16) x W(f16)^T, split-K=4 -> 4 partials, then reduce -> h f16 hi
        mgemm128f_k<<<dim3(6, 13, 4), 256, 0, stream>>>(yh,
            woh + (size_t)l * 1179648,
            opart, M_ROWS, DD, DI, DI, (long)M_ROWS * DD);
        red4hi_k<<<(M_ROWS * DD / 4 + 255) / 256, 256, 0, stream>>>(
            opart, hbh, M_ROWS * DD / 4, M_ROWS * DD / 4);
    }

    ln_k<<<M_ROWS, 256, 0, stream>>>(hbh, norm_w, norm_b, out);
}